// Round 4
// baseline (205.348 us; speedup 1.0000x reference)
//
#include <hip/hip_runtime.h>
#include <hip/hip_bf16.h>

#define S_SRC 4096
#define DIM 128
#define BATCH 2
#define KSPLIT 4
#define NQG 512  // 16-row q-groups total (BATCH*S_SRC/16)

typedef unsigned short u16;
typedef __bf16 bf16x8 __attribute__((ext_vector_type(8)));
typedef float f32x4 __attribute__((ext_vector_type(4)));

__device__ __forceinline__ __bf16 bf_hi(float x) { return (__bf16)x; }
__device__ __forceinline__ __bf16 bf_lo(float x, __bf16 h) { return (__bf16)(x - (float)h); }
__device__ __forceinline__ u16 bfu(__bf16 h) { return __builtin_bit_cast(u16, h); }
__device__ __forceinline__ u16 f2bu(float x) { return __builtin_bit_cast(u16, (__bf16)x); }

// ---------------- kernel 0: transpose + hi/lo split the weight matrices ----------------
__global__ __launch_bounds__(256) void k_wsplit(const float* __restrict__ wq,
                                                const float* __restrict__ wk,
                                                const float* __restrict__ wv,
                                                u16* __restrict__ wt) {
  int idx = blockIdx.x * 256 + threadIdx.x;  // 3*128*128 = 49152
  int mat = idx >> 14;
  int r = idx & 16383;
  int d = r >> 7, e = r & 127;
  const float* w = (mat == 0) ? wq : ((mat == 1) ? wk : wv);
  float x = w[r];
  if (mat == 0) x *= 0.08838834764831845f;  // fold 1/sqrt(128) into Wq
  __bf16 h = bf_hi(x);
  __bf16 l = bf_lo(x, h);
  wt[((mat * 2 + 0) * 128 + e) * 128 + d] = bfu(h);
  wt[((mat * 2 + 1) * 128 + e) * 128 + d] = bfu(l);
}

// ---------------- kernel 1: QKV projection (bf16 hi/lo, 3-product MFMA) ----------------
__global__ __launch_bounds__(256) void k_proj(const float* __restrict__ X,
                                              const u16* __restrict__ wt,
                                              u16* __restrict__ Qh, u16* __restrict__ Ql,
                                              u16* __restrict__ Kh, u16* __restrict__ Kl,
                                              u16* __restrict__ VT) {
  const int b = blockIdx.x >> 7;
  const int tile = blockIdx.x & 127;
  const int tid = threadIdx.x;
  const int w = tid >> 6, lane = tid & 63, g = lane >> 4, l16 = lane & 15;

  bf16x8 a_h[2][4], a_l[2][4];
#pragma unroll
  for (int mf = 0; mf < 2; ++mf) {
    int row = tile * 32 + mf * 16 + l16;
    const float* xr = X + ((size_t)b * S_SRC + row) * DIM;
#pragma unroll
    for (int kf = 0; kf < 4; ++kf) {
      int d0 = kf * 32 + g * 8;
      f32x4 x0 = *(const f32x4*)(xr + d0);
      f32x4 x1 = *(const f32x4*)(xr + d0 + 4);
#pragma unroll
      for (int j = 0; j < 4; ++j) {
        __bf16 h0 = bf_hi(x0[j]);
        __bf16 h1 = bf_hi(x1[j]);
        a_h[mf][kf][j] = h0;
        a_l[mf][kf][j] = bf_lo(x0[j], h0);
        a_h[mf][kf][4 + j] = h1;
        a_l[mf][kf][4 + j] = bf_lo(x1[j], h1);
      }
    }
  }

#pragma unroll
  for (int mat = 0; mat < 3; ++mat) {
    const u16* wth = wt + (mat * 2 + 0) * 16384;
    const u16* wtl = wt + (mat * 2 + 1) * 16384;
#pragma unroll
    for (int nf = 0; nf < 2; ++nf) {
      int col = w * 32 + nf * 16 + l16;
      f32x4 acc[2];
      acc[0] = (f32x4){0.f, 0.f, 0.f, 0.f};
      acc[1] = (f32x4){0.f, 0.f, 0.f, 0.f};
#pragma unroll
      for (int kf = 0; kf < 4; ++kf) {
        int d0 = kf * 32 + g * 8;
        bf16x8 bh = *(const bf16x8*)(const void*)(wth + col * 128 + d0);
        bf16x8 bl = *(const bf16x8*)(const void*)(wtl + col * 128 + d0);
#pragma unroll
        for (int mf = 0; mf < 2; ++mf) {
          acc[mf] = __builtin_amdgcn_mfma_f32_16x16x32_bf16(a_h[mf][kf], bh, acc[mf], 0, 0, 0);
          acc[mf] = __builtin_amdgcn_mfma_f32_16x16x32_bf16(a_h[mf][kf], bl, acc[mf], 0, 0, 0);
          acc[mf] = __builtin_amdgcn_mfma_f32_16x16x32_bf16(a_l[mf][kf], bh, acc[mf], 0, 0, 0);
        }
      }
#pragma unroll
      for (int mf = 0; mf < 2; ++mf)
#pragma unroll
        for (int r = 0; r < 4; ++r) {
          int row = tile * 32 + mf * 16 + g * 4 + r;
          float v = acc[mf][r];
          if (mat == 2) {
            VT[((size_t)b * DIM + col) * S_SRC + row] = f2bu(v);
          } else {
            __bf16 h = bf_hi(v);
            __bf16 l = bf_lo(v, h);
            size_t o = ((size_t)b * S_SRC + row) * DIM + col;
            if (mat == 0) { Qh[o] = bfu(h); Ql[o] = bfu(l); }
            else          { Kh[o] = bfu(h); Kl[o] = bfu(l); }
          }
        }
    }
  }
}

// ---------------- kernel 2: flash attention, 1-wave blocks, 16 rows/wave ----------------
__global__ __launch_bounds__(64, 3) void k_attn(const u16* __restrict__ Qh, const u16* __restrict__ Ql,
                                                const u16* __restrict__ Kh, const u16* __restrict__ Kl,
                                                const u16* __restrict__ VT,
                                                float* __restrict__ Pm, float* __restrict__ Pl,
                                                float* __restrict__ PO) {
  // XCD-aware bijective remap: 2048 blocks = 8 XCDs x 256. Each XCD sees one (batch, split).
  const int bid = blockIdx.x;
  const int lid = (bid & 7) * 256 + (bid >> 3);
  const int sp = lid >> 9;   // kv split 0..3
  const int qg = lid & 511;  // 16-row q-group 0..511
  const int b = qg >> 8;
  const int lane = threadIdx.x;
  const int g = lane >> 4, l16 = lane & 15;

  __shared__ alignas(16) u16 p_lds[16][40];  // 1.3 KB

  // Q fragments (hi/lo) for rows qg*16 .. +15
  bf16x8 q_h[4], q_l[4];
  {
    const u16* qph = Qh + ((size_t)qg * 16 + l16) * DIM;
    const u16* qpl = Ql + ((size_t)qg * 16 + l16) * DIM;
#pragma unroll
    for (int kf = 0; kf < 4; ++kf) {
      int d0 = kf * 32 + g * 8;
      q_h[kf] = *(const bf16x8*)(const void*)(qph + d0);
      q_l[kf] = *(const bf16x8*)(const void*)(qpl + d0);
    }
  }

  f32x4 acc[8];
#pragma unroll
  for (int nf = 0; nf < 8; ++nf) acc[nf] = (f32x4){0.f, 0.f, 0.f, 0.f};
  float m_run[4], l_run[4];
#pragma unroll
  for (int r = 0; r < 4; ++r) { m_run[r] = -1e30f; l_run[r] = 0.f; }

  for (int t = sp * 32; t < (sp + 1) * 32; ++t) {
    const int key0 = t * 32;
    // ---- scores: S = Q Khat^T (3-product hi/lo), 16 rows x 32 keys ----
    f32x4 sacc[2];
    sacc[0] = (f32x4){0.f, 0.f, 0.f, 0.f};
    sacc[1] = (f32x4){0.f, 0.f, 0.f, 0.f};
    __builtin_amdgcn_s_setprio(1);
#pragma unroll
    for (int nf = 0; nf < 2; ++nf) {
      const u16* kbh = Kh + ((size_t)b * S_SRC + key0 + nf * 16 + l16) * DIM;
      const u16* kbl = Kl + ((size_t)b * S_SRC + key0 + nf * 16 + l16) * DIM;
#pragma unroll
      for (int kf = 0; kf < 4; ++kf) {
        int d0 = kf * 32 + g * 8;
        bf16x8 kh = *(const bf16x8*)(const void*)(kbh + d0);
        bf16x8 kl = *(const bf16x8*)(const void*)(kbl + d0);
        sacc[nf] = __builtin_amdgcn_mfma_f32_16x16x32_bf16(q_h[kf], kh, sacc[nf], 0, 0, 0);
        sacc[nf] = __builtin_amdgcn_mfma_f32_16x16x32_bf16(q_h[kf], kl, sacc[nf], 0, 0, 0);
        sacc[nf] = __builtin_amdgcn_mfma_f32_16x16x32_bf16(q_l[kf], kh, sacc[nf], 0, 0, 0);
      }
    }
    __builtin_amdgcn_s_setprio(0);
    // ---- online softmax (row = g*4+r, keys across l16 lanes x 2 frags) ----
    float fac[4];
#pragma unroll
    for (int r = 0; r < 4; ++r) {
      float s0 = sacc[0][r], s1 = sacc[1][r];
      float v = fmaxf(s0, s1);
      v = fmaxf(v, __shfl_xor(v, 1, 64));
      v = fmaxf(v, __shfl_xor(v, 2, 64));
      v = fmaxf(v, __shfl_xor(v, 4, 64));
      v = fmaxf(v, __shfl_xor(v, 8, 64));
      float mo = m_run[r];
      float mn = fmaxf(mo, v);
      float f = __expf(mo - mn);
      fac[r] = f;
      float p0 = __expf(s0 - mn);
      float p1 = __expf(s1 - mn);
      float sm = p0 + p1;
      sm += __shfl_xor(sm, 1, 64);
      sm += __shfl_xor(sm, 2, 64);
      sm += __shfl_xor(sm, 4, 64);
      sm += __shfl_xor(sm, 8, 64);
      l_run[r] = l_run[r] * f + sm;
      m_run[r] = mn;
      int row = g * 4 + r;
      p_lds[row][l16] = f2bu(p0);
      p_lds[row][16 + l16] = f2bu(p1);
    }
#pragma unroll
    for (int nf = 0; nf < 8; ++nf)
#pragma unroll
      for (int r = 0; r < 4; ++r) acc[nf][r] *= fac[r];
    // P: C-frag layout -> A-frag layout via tiny LDS bounce (single wave, no barrier)
    asm volatile("s_waitcnt lgkmcnt(0)" ::: "memory");
    __builtin_amdgcn_sched_barrier(0);
    bf16x8 pa = *(const bf16x8*)(const void*)(&p_lds[l16][g * 8]);
    // ---- PV: O += P * V ----
    __builtin_amdgcn_s_setprio(1);
#pragma unroll
    for (int nf = 0; nf < 8; ++nf) {
      int dcol = nf * 16 + l16;
      bf16x8 vf = *(const bf16x8*)(const void*)(VT + ((size_t)b * DIM + dcol) * S_SRC + key0 + g * 8);
      acc[nf] = __builtin_amdgcn_mfma_f32_16x16x32_bf16(pa, vf, acc[nf], 0, 0, 0);
    }
    __builtin_amdgcn_s_setprio(0);
  }

  // ---- write partial (m, l, O) for this (q-group, split) ----
  const int pidx = sp * NQG + qg;
  float* po = PO + (size_t)pidx * 16 * DIM;
#pragma unroll
  for (int nf = 0; nf < 8; ++nf)
#pragma unroll
    for (int r = 0; r < 4; ++r)
      po[(g * 4 + r) * DIM + nf * 16 + l16] = acc[nf][r];
  if (l16 == 0) {
#pragma unroll
    for (int r = 0; r < 4; ++r) {
      Pm[pidx * 16 + g * 4 + r] = m_run[r];
      Pl[pidx * 16 + g * 4 + r] = l_run[r];
    }
  }
}

// ---------------- kernel 3: combine KV-split partials ----------------
__global__ __launch_bounds__(64) void k_comb(const float* __restrict__ Pm,
                                             const float* __restrict__ Pl,
                                             const float* __restrict__ PO,
                                             float* __restrict__ out) {
  const int qg = blockIdx.x;
  const int tid = threadIdx.x;

  __shared__ float sc[KSPLIT][16];
  if (tid < 16) {
    float m = -1e30f;
#pragma unroll
    for (int s = 0; s < KSPLIT; ++s) m = fmaxf(m, Pm[(s * NQG + qg) * 16 + tid]);
    float den = 0.f;
    float e[KSPLIT];
#pragma unroll
    for (int s = 0; s < KSPLIT; ++s) {
      e[s] = __expf(Pm[(s * NQG + qg) * 16 + tid] - m);
      den += Pl[(s * NQG + qg) * 16 + tid] * e[s];
    }
    float inv = 1.0f / den;
#pragma unroll
    for (int s = 0; s < KSPLIT; ++s) sc[s][tid] = e[s] * inv;
  }
  __syncthreads();

  float* op = out + (size_t)qg * 16 * DIM;
  for (int i = tid; i < 16 * DIM; i += 64) {
    int row = i >> 7;
    float acc = 0.f;
#pragma unroll
    for (int s = 0; s < KSPLIT; ++s)
      acc += PO[(size_t)(s * NQG + qg) * 16 * DIM + i] * sc[s][row];
    op[i] = acc;
  }
}

extern "C" void kernel_launch(void* const* d_in, const int* in_sizes, int n_in,
                              void* d_out, int out_size, void* d_ws, size_t ws_size,
                              hipStream_t stream) {
  const float* X  = (const float*)d_in[0];
  const float* wq = (const float*)d_in[4];
  const float* wk = (const float*)d_in[5];
  const float* wv = (const float*)d_in[6];
  float* out = (float*)d_out;

  u16* WT = (u16*)d_ws;                       // 3*2*128*128 u16 = 192 KiB
  u16* Qh = WT + 3 * 2 * 128 * 128;
  u16* Ql = Qh + (size_t)BATCH * S_SRC * DIM; // 2 MiB each
  u16* Kh = Ql + (size_t)BATCH * S_SRC * DIM;
  u16* Kl = Kh + (size_t)BATCH * S_SRC * DIM;
  u16* VT = Kl + (size_t)BATCH * S_SRC * DIM; // [B][D][S]
  float* Pm = (float*)(VT + (size_t)BATCH * S_SRC * DIM);  // [KSPLIT*NQG*16]
  float* Pl = Pm + (size_t)KSPLIT * NQG * 16;
  float* PO = Pl + (size_t)KSPLIT * NQG * 16;              // [KSPLIT*NQG*16*128] f32 = 16 MiB

  hipLaunchKernelGGL(k_wsplit, dim3(192), dim3(256), 0, stream, wq, wk, wv, WT);
  hipLaunchKernelGGL(k_proj, dim3(BATCH * S_SRC / 32), dim3(256), 0, stream,
                     X, WT, Qh, Ql, Kh, Kl, VT);
  hipLaunchKernelGGL(k_attn, dim3(NQG * KSPLIT), dim3(64), 0, stream,
                     Qh, Ql, Kh, Kl, VT, Pm, Pl, PO);
  hipLaunchKernelGGL(k_comb, dim3(NQG), dim3(64), 0, stream, Pm, Pl, PO, out);
}

// Round 5
// 84.126 us; speedup vs baseline: 2.4410x; 2.4410x over previous
//
#include <hip/hip_runtime.h>
#include <hip/hip_bf16.h>

#define S_SRC 4096
#define DIM 128
#define BATCH 2
#define KSPLIT 4
#define NQG 512  // 16-row q-groups total (BATCH*S_SRC/16)

typedef unsigned short u16;
typedef unsigned int u32;
typedef __bf16 bf16x8 __attribute__((ext_vector_type(8)));
typedef float f32x4 __attribute__((ext_vector_type(4)));
typedef u32 u32x4 __attribute__((ext_vector_type(4)));

__device__ __forceinline__ __bf16 bf_hi(float x) { return (__bf16)x; }
__device__ __forceinline__ __bf16 bf_lo(float x, __bf16 h) { return (__bf16)(x - (float)h); }
__device__ __forceinline__ u16 bfu(__bf16 h) { return __builtin_bit_cast(u16, h); }
__device__ __forceinline__ u16 f2bu(float x) { return __builtin_bit_cast(u16, (__bf16)x); }
__device__ __forceinline__ u32 pk2(float lo, float hi) {
  return (u32)f2bu(lo) | ((u32)f2bu(hi) << 16);
}
__device__ __forceinline__ void g2l16(const u16* src, u16* ldst) {
  __builtin_amdgcn_global_load_lds((const __attribute__((address_space(1))) void*)src,
                                   (__attribute__((address_space(3))) void*)ldst, 16, 0, 0);
}

// ---------------- kernel 0: transpose + hi/lo split the weight matrices ----------------
__global__ __launch_bounds__(256) void k_wsplit(const float* __restrict__ wq,
                                                const float* __restrict__ wk,
                                                const float* __restrict__ wv,
                                                u16* __restrict__ wt) {
  int idx = blockIdx.x * 256 + threadIdx.x;  // 3*128*128 = 49152
  int mat = idx >> 14;
  int r = idx & 16383;
  int d = r >> 7, e = r & 127;
  const float* w = (mat == 0) ? wq : ((mat == 1) ? wk : wv);
  float x = w[r];
  if (mat == 0) x *= 0.08838834764831845f;  // fold 1/sqrt(128) into Wq
  __bf16 h = bf_hi(x);
  __bf16 l = bf_lo(x, h);
  wt[((mat * 2 + 0) * 128 + e) * 128 + d] = bfu(h);
  wt[((mat * 2 + 1) * 128 + e) * 128 + d] = bfu(l);
}

// ---------------- kernel 1: QKV projection (bf16 hi/lo, 3-product MFMA) ----------------
__global__ __launch_bounds__(256) void k_proj(const float* __restrict__ X,
                                              const u16* __restrict__ wt,
                                              u16* __restrict__ Qh, u16* __restrict__ Ql,
                                              u16* __restrict__ Kh, u16* __restrict__ Kl,
                                              u16* __restrict__ VT) {
  const int b = blockIdx.x >> 7;
  const int tile = blockIdx.x & 127;
  const int tid = threadIdx.x;
  const int w = tid >> 6, lane = tid & 63, g = lane >> 4, l16 = lane & 15;

  bf16x8 a_h[2][4], a_l[2][4];
#pragma unroll
  for (int mf = 0; mf < 2; ++mf) {
    int row = tile * 32 + mf * 16 + l16;
    const float* xr = X + ((size_t)b * S_SRC + row) * DIM;
#pragma unroll
    for (int kf = 0; kf < 4; ++kf) {
      int d0 = kf * 32 + g * 8;
      f32x4 x0 = *(const f32x4*)(xr + d0);
      f32x4 x1 = *(const f32x4*)(xr + d0 + 4);
#pragma unroll
      for (int j = 0; j < 4; ++j) {
        __bf16 h0 = bf_hi(x0[j]);
        __bf16 h1 = bf_hi(x1[j]);
        a_h[mf][kf][j] = h0;
        a_l[mf][kf][j] = bf_lo(x0[j], h0);
        a_h[mf][kf][4 + j] = h1;
        a_l[mf][kf][4 + j] = bf_lo(x1[j], h1);
      }
    }
  }

#pragma unroll
  for (int mat = 0; mat < 3; ++mat) {
    const u16* wth = wt + (mat * 2 + 0) * 16384;
    const u16* wtl = wt + (mat * 2 + 1) * 16384;
#pragma unroll
    for (int nf = 0; nf < 2; ++nf) {
      int col = w * 32 + nf * 16 + l16;
      f32x4 acc[2];
      acc[0] = (f32x4){0.f, 0.f, 0.f, 0.f};
      acc[1] = (f32x4){0.f, 0.f, 0.f, 0.f};
#pragma unroll
      for (int kf = 0; kf < 4; ++kf) {
        int d0 = kf * 32 + g * 8;
        bf16x8 bh = *(const bf16x8*)(const void*)(wth + col * 128 + d0);
        bf16x8 bl = *(const bf16x8*)(const void*)(wtl + col * 128 + d0);
#pragma unroll
        for (int mf = 0; mf < 2; ++mf) {
          acc[mf] = __builtin_amdgcn_mfma_f32_16x16x32_bf16(a_h[mf][kf], bh, acc[mf], 0, 0, 0);
          acc[mf] = __builtin_amdgcn_mfma_f32_16x16x32_bf16(a_h[mf][kf], bl, acc[mf], 0, 0, 0);
          acc[mf] = __builtin_amdgcn_mfma_f32_16x16x32_bf16(a_l[mf][kf], bh, acc[mf], 0, 0, 0);
        }
      }
#pragma unroll
      for (int mf = 0; mf < 2; ++mf)
#pragma unroll
        for (int r = 0; r < 4; ++r) {
          int row = tile * 32 + mf * 16 + g * 4 + r;
          float v = acc[mf][r];
          if (mat == 2) {
            VT[((size_t)b * DIM + col) * S_SRC + row] = f2bu(v);
          } else {
            __bf16 h = bf_hi(v);
            __bf16 l = bf_lo(v, h);
            size_t o = ((size_t)b * S_SRC + row) * DIM + col;
            if (mat == 0) { Qh[o] = bfu(h); Ql[o] = bfu(l); }
            else          { Kh[o] = bfu(h); Kl[o] = bfu(l); }
          }
        }
    }
  }
}

// ---------------- kernel 2: flash attention, 8 waves share LDS-staged KV tile ----------------
// Block: 128 q-rows (8 waves x 16), 1024 keys (KSPLIT=4). Swapped QK^T (A=K, B=Q):
// lane (g,l16): sacc[nf][r] = S[key = nf*16 + g*4 + r][q-row = l16] -> softmax lane-local.
__global__ __launch_bounds__(512, 2) void k_attn(const u16* __restrict__ Qh, const u16* __restrict__ Ql,
                                                 const u16* __restrict__ Kh, const u16* __restrict__ Kl,
                                                 const u16* __restrict__ VT,
                                                 float* __restrict__ Pm, float* __restrict__ Pl,
                                                 float* __restrict__ PO) {
  const int qb = blockIdx.x & 63;   // 128-row q-block
  const int sp = blockIdx.x >> 6;   // kv split 0..3
  const int b = qb >> 5;
  const int tid = threadIdx.x;
  const int w = tid >> 6, lane = tid & 63, g = lane >> 4, l16 = lane & 15;

  // K: [2 buf][hi 32x(128+swz) | lo], V: [2 buf][128d x 32s swz]
  __shared__ alignas(16) u16 kbuf[2][8192];   // 16KB each
  __shared__ alignas(16) u16 vbuf[2][4096];   // 8KB each

  // ---- Q fragments (hi/lo), q-rows qb*128 + w*16 .. +15 ----
  const int gr0 = qb * 128 + w * 16;
  bf16x8 q_h[4], q_l[4];
  {
    const u16* qph = Qh + ((size_t)gr0 + l16) * DIM;
    const u16* qpl = Ql + ((size_t)gr0 + l16) * DIM;
#pragma unroll
    for (int kf = 0; kf < 4; ++kf) {
      int d0 = kf * 32 + g * 8;
      q_h[kf] = *(const bf16x8*)(const void*)(qph + d0);
      q_l[kf] = *(const bf16x8*)(const void*)(qpl + d0);
    }
  }

  f32x4 acc[8];
#pragma unroll
  for (int nf = 0; nf < 8; ++nf) acc[nf] = (f32x4){0.f, 0.f, 0.f, 0.f};
  float m_run = -1e30f, l_run = 0.f;   // stats of q-row l16

  const int key_base = sp * (S_SRC / KSPLIT);
  const u16* KhB = Kh + (size_t)b * S_SRC * DIM;
  const u16* KlB = Kl + (size_t)b * S_SRC * DIM;
  const u16* VTB = VT + (size_t)b * DIM * S_SRC;

  // stage tile (32 keys) into buffer: K hi/lo chunk-XOR swizzled, V chunk-XOR swizzled
  const int kkey = tid >> 4, kcp = tid & 15;                 // K chunk (key, slot)
  const int kcs = (kcp ^ (kkey & 15)) << 3;                  // source d-offset (elems)
  const int vd = tid >> 2, vcp = tid & 3;                    // V chunk (d, slot)
  const int vcs = (vcp ^ ((vd >> 1) & 3)) << 3;              // source s-offset (elems)
  const int wbase = w * 512;                                 // wave-uniform LDS chunk base (u16)

#define STAGE(BUF, KEY0)                                                        \
  {                                                                             \
    const u16* sH = KhB + ((size_t)((KEY0) + kkey)) * DIM + kcs;                \
    const u16* sL = KlB + ((size_t)((KEY0) + kkey)) * DIM + kcs;                \
    const u16* sV = VTB + (size_t)vd * S_SRC + (KEY0) + vcs;                    \
    g2l16(sH, &kbuf[BUF][wbase]);                                               \
    g2l16(sL, &kbuf[BUF][4096 + wbase]);                                        \
    g2l16(sV, &vbuf[BUF][wbase]);                                               \
  }

  STAGE(0, key_base)

  const int mg = ((g & 1) << 1) | (g >> 1);  // V key-chunk permutation {0,2,1,3}
  int cur = 0;
  for (int i = 0; i < S_SRC / KSPLIT / 32; ++i) {
    if (i + 1 < S_SRC / KSPLIT / 32) {
      STAGE(cur ^ 1, key_base + (i + 1) * 32)
      asm volatile("s_waitcnt vmcnt(3)" ::: "memory");
    } else {
      asm volatile("s_waitcnt vmcnt(0)" ::: "memory");
    }
    __builtin_amdgcn_s_barrier();

    // ---- QK^T swapped: sacc[nf] rows = keys, cols = q ----
    const u16* kb = kbuf[cur];
    f32x4 s0 = (f32x4){0.f, 0.f, 0.f, 0.f};
    f32x4 s1 = (f32x4){0.f, 0.f, 0.f, 0.f};
    __builtin_amdgcn_s_setprio(1);
#pragma unroll
    for (int kf = 0; kf < 4; ++kf) {
      int cs = ((kf * 4 + g) ^ l16) << 3;
      bf16x8 kh0 = *(const bf16x8*)(const void*)(kb + l16 * 128 + cs);
      bf16x8 kl0 = *(const bf16x8*)(const void*)(kb + 4096 + l16 * 128 + cs);
      bf16x8 kh1 = *(const bf16x8*)(const void*)(kb + (16 + l16) * 128 + cs);
      bf16x8 kl1 = *(const bf16x8*)(const void*)(kb + 4096 + (16 + l16) * 128 + cs);
      s0 = __builtin_amdgcn_mfma_f32_16x16x32_bf16(kh0, q_h[kf], s0, 0, 0, 0);
      s0 = __builtin_amdgcn_mfma_f32_16x16x32_bf16(kh0, q_l[kf], s0, 0, 0, 0);
      s0 = __builtin_amdgcn_mfma_f32_16x16x32_bf16(kl0, q_h[kf], s0, 0, 0, 0);
      s1 = __builtin_amdgcn_mfma_f32_16x16x32_bf16(kh1, q_h[kf], s1, 0, 0, 0);
      s1 = __builtin_amdgcn_mfma_f32_16x16x32_bf16(kh1, q_l[kf], s1, 0, 0, 0);
      s1 = __builtin_amdgcn_mfma_f32_16x16x32_bf16(kl1, q_h[kf], s1, 0, 0, 0);
    }
    __builtin_amdgcn_s_setprio(0);

    // ---- softmax: q-row l16 is lane-local over 8 scores + 2 shfl ----
    float mx = fmaxf(fmaxf(fmaxf(s0[0], s0[1]), fmaxf(s0[2], s0[3])),
                     fmaxf(fmaxf(s1[0], s1[1]), fmaxf(s1[2], s1[3])));
    mx = fmaxf(mx, __shfl_xor(mx, 16, 64));
    mx = fmaxf(mx, __shfl_xor(mx, 32, 64));
    float mn = fmaxf(m_run, mx);
    float f = __expf(m_run - mn);
    float e0 = __expf(s0[0] - mn), e1 = __expf(s0[1] - mn);
    float e2 = __expf(s0[2] - mn), e3 = __expf(s0[3] - mn);
    float e4 = __expf(s1[0] - mn), e5 = __expf(s1[1] - mn);
    float e6 = __expf(s1[2] - mn), e7 = __expf(s1[3] - mn);
    float sm = ((e0 + e1) + (e2 + e3)) + ((e4 + e5) + (e6 + e7));
    sm += __shfl_xor(sm, 16, 64);
    sm += __shfl_xor(sm, 32, 64);
    l_run = l_run * f + sm;
    m_run = mn;

    // rescale acc rows (q = g*4+r) by fac of that row
    float fr0 = __shfl(f, g * 4 + 0, 64);
    float fr1 = __shfl(f, g * 4 + 1, 64);
    float fr2 = __shfl(f, g * 4 + 2, 64);
    float fr3 = __shfl(f, g * 4 + 3, 64);
#pragma unroll
    for (int nf = 0; nf < 8; ++nf) {
      acc[nf][0] *= fr0; acc[nf][1] *= fr1; acc[nf][2] *= fr2; acc[nf][3] *= fr3;
    }

    // ---- P -> A-frag: pack pairs, one xor-16 exchange, parity select ----
    u32 w0 = pk2(e0, e1), w1 = pk2(e2, e3), w2 = pk2(e4, e5), w3 = pk2(e6, e7);
    u32 x0 = __shfl_xor(w0, 16, 64), x1 = __shfl_xor(w1, 16, 64);
    u32 x2 = __shfl_xor(w2, 16, 64), x3 = __shfl_xor(w3, 16, 64);
    bool odd = (g & 1);
    u32x4 pw;
    pw.x = odd ? x2 : w0;
    pw.y = odd ? x3 : w1;
    pw.z = odd ? w2 : x0;
    pw.w = odd ? w3 : x1;
    bf16x8 pa = __builtin_bit_cast(bf16x8, pw);

    // ---- PV: O += P * V (V key-slots permuted to match pa: kappa(g) = mg*8) ----
    const u16* vb = vbuf[cur];
    __builtin_amdgcn_s_setprio(1);
#pragma unroll
    for (int nf = 0; nf < 8; ++nf) {
      int d = nf * 16 + l16;
      bf16x8 vf = *(const bf16x8*)(const void*)(vb + d * 32 + ((mg ^ ((d >> 1) & 3)) << 3));
      acc[nf] = __builtin_amdgcn_mfma_f32_16x16x32_bf16(pa, vf, acc[nf], 0, 0, 0);
    }
    __builtin_amdgcn_s_setprio(0);

    __builtin_amdgcn_s_barrier();
    cur ^= 1;
  }

  // ---- write partial (m, l, O) for this (16-row group, split) ----
  const int pidx = sp * NQG + (gr0 >> 4);
  float* po = PO + (size_t)pidx * 16 * DIM;
#pragma unroll
  for (int nf = 0; nf < 8; ++nf)
#pragma unroll
    for (int r = 0; r < 4; ++r)
      po[(g * 4 + r) * DIM + nf * 16 + l16] = acc[nf][r];
  if (lane < 16) {
    Pm[pidx * 16 + l16] = m_run;
    Pl[pidx * 16 + l16] = l_run;
  }
#undef STAGE
}

// ---------------- kernel 3: combine KV-split partials ----------------
__global__ __launch_bounds__(64) void k_comb(const float* __restrict__ Pm,
                                             const float* __restrict__ Pl,
                                             const float* __restrict__ PO,
                                             float* __restrict__ out) {
  const int qg = blockIdx.x;
  const int tid = threadIdx.x;

  __shared__ float sc[KSPLIT][16];
  if (tid < 16) {
    float m = -1e30f;
#pragma unroll
    for (int s = 0; s < KSPLIT; ++s) m = fmaxf(m, Pm[(s * NQG + qg) * 16 + tid]);
    float den = 0.f;
    float e[KSPLIT];
#pragma unroll
    for (int s = 0; s < KSPLIT; ++s) {
      e[s] = __expf(Pm[(s * NQG + qg) * 16 + tid] - m);
      den += Pl[(s * NQG + qg) * 16 + tid] * e[s];
    }
    float inv = 1.0f / den;
#pragma unroll
    for (int s = 0; s < KSPLIT; ++s) sc[s][tid] = e[s] * inv;
  }
  __syncthreads();

  float* op = out + (size_t)qg * 16 * DIM;
  for (int i = tid; i < 16 * DIM; i += 64) {
    int row = i >> 7;
    float acc = 0.f;
#pragma unroll
    for (int s = 0; s < KSPLIT; ++s)
      acc += PO[(size_t)(s * NQG + qg) * 16 * DIM + i] * sc[s][row];
    op[i] = acc;
  }
}

extern "C" void kernel_launch(void* const* d_in, const int* in_sizes, int n_in,
                              void* d_out, int out_size, void* d_ws, size_t ws_size,
                              hipStream_t stream) {
  const float* X  = (const float*)d_in[0];
  const float* wq = (const float*)d_in[4];
  const float* wk = (const float*)d_in[5];
  const float* wv = (const float*)d_in[6];
  float* out = (float*)d_out;

  u16* WT = (u16*)d_ws;                       // 3*2*128*128 u16 = 192 KiB
  u16* Qh = WT + 3 * 2 * 128 * 128;
  u16* Ql = Qh + (size_t)BATCH * S_SRC * DIM; // 2 MiB each
  u16* Kh = Ql + (size_t)BATCH * S_SRC * DIM;
  u16* Kl = Kh + (size_t)BATCH * S_SRC * DIM;
  u16* VT = Kl + (size_t)BATCH * S_SRC * DIM; // [B][D][S]
  float* Pm = (float*)(VT + (size_t)BATCH * S_SRC * DIM);  // [KSPLIT*NQG*16]
  float* Pl = Pm + (size_t)KSPLIT * NQG * 16;
  float* PO = Pl + (size_t)KSPLIT * NQG * 16;              // [KSPLIT*NQG*16*128] f32 = 16 MiB

  hipLaunchKernelGGL(k_wsplit, dim3(192), dim3(256), 0, stream, wq, wk, wv, WT);
  hipLaunchKernelGGL(k_proj, dim3(BATCH * S_SRC / 32), dim3(256), 0, stream,
                     X, WT, Qh, Ql, Kh, Kl, VT);
  hipLaunchKernelGGL(k_attn, dim3(64 * KSPLIT), dim3(512), 0, stream,
                     Qh, Ql, Kh, Kl, VT, Pm, Pl, PO);
  hipLaunchKernelGGL(k_comb, dim3(NQG), dim3(64), 0, stream, Pm, Pl, PO, out);
}

// Round 6
// 73.551 us; speedup vs baseline: 2.7919x; 1.1438x over previous
//
#include <hip/hip_runtime.h>
#include <hip/hip_bf16.h>

#define S_SRC 4096
#define DIM 128
#define BATCH 2
#define KSPLIT 8
#define NQG 512  // 16-row q-groups total (BATCH*S_SRC/16)

typedef unsigned short u16;
typedef unsigned int u32;
typedef __bf16 bf16x8 __attribute__((ext_vector_type(8)));
typedef float f32x4 __attribute__((ext_vector_type(4)));
typedef u32 u32x4 __attribute__((ext_vector_type(4)));

__device__ __forceinline__ __bf16 bf_hi(float x) { return (__bf16)x; }
__device__ __forceinline__ __bf16 bf_lo(float x, __bf16 h) { return (__bf16)(x - (float)h); }
__device__ __forceinline__ u16 bfu(__bf16 h) { return __builtin_bit_cast(u16, h); }
__device__ __forceinline__ u16 f2bu(float x) { return __builtin_bit_cast(u16, (__bf16)x); }
__device__ __forceinline__ float bu2f(u16 u) { return (float)__builtin_bit_cast(__bf16, u); }
__device__ __forceinline__ u32 pk2(float lo, float hi) {
  return (u32)f2bu(lo) | ((u32)f2bu(hi) << 16);
}
__device__ __forceinline__ void g2l16(const u16* src, u16* ldst) {
  __builtin_amdgcn_global_load_lds((const __attribute__((address_space(1))) void*)src,
                                   (__attribute__((address_space(3))) void*)ldst, 16, 0, 0);
}

// ---------------- kernel 0: transpose + hi/lo split the weight matrices ----------------
__global__ __launch_bounds__(256) void k_wsplit(const float* __restrict__ wq,
                                                const float* __restrict__ wk,
                                                const float* __restrict__ wv,
                                                u16* __restrict__ wt) {
  int idx = blockIdx.x * 256 + threadIdx.x;  // 3*128*128 = 49152
  int mat = idx >> 14;
  int r = idx & 16383;
  int d = r >> 7, e = r & 127;
  const float* w = (mat == 0) ? wq : ((mat == 1) ? wk : wv);
  float x = w[r];
  if (mat == 0) x *= 0.08838834764831845f;  // fold 1/sqrt(128) into Wq
  __bf16 h = bf_hi(x);
  __bf16 l = bf_lo(x, h);
  wt[((mat * 2 + 0) * 128 + e) * 128 + d] = bfu(h);
  wt[((mat * 2 + 1) * 128 + e) * 128 + d] = bfu(l);
}

// ---------------- kernel 1: QKV projection (bf16 hi/lo, 3-product MFMA) ----------------
__global__ __launch_bounds__(256) void k_proj(const float* __restrict__ X,
                                              const u16* __restrict__ wt,
                                              u16* __restrict__ Qh, u16* __restrict__ Ql,
                                              u16* __restrict__ Kh, u16* __restrict__ Kl,
                                              u16* __restrict__ VT) {
  const int b = blockIdx.x >> 7;
  const int tile = blockIdx.x & 127;
  const int tid = threadIdx.x;
  const int w = tid >> 6, lane = tid & 63, g = lane >> 4, l16 = lane & 15;

  bf16x8 a_h[2][4], a_l[2][4];
#pragma unroll
  for (int mf = 0; mf < 2; ++mf) {
    int row = tile * 32 + mf * 16 + l16;
    const float* xr = X + ((size_t)b * S_SRC + row) * DIM;
#pragma unroll
    for (int kf = 0; kf < 4; ++kf) {
      int d0 = kf * 32 + g * 8;
      f32x4 x0 = *(const f32x4*)(xr + d0);
      f32x4 x1 = *(const f32x4*)(xr + d0 + 4);
#pragma unroll
      for (int j = 0; j < 4; ++j) {
        __bf16 h0 = bf_hi(x0[j]);
        __bf16 h1 = bf_hi(x1[j]);
        a_h[mf][kf][j] = h0;
        a_l[mf][kf][j] = bf_lo(x0[j], h0);
        a_h[mf][kf][4 + j] = h1;
        a_l[mf][kf][4 + j] = bf_lo(x1[j], h1);
      }
    }
  }

#pragma unroll
  for (int mat = 0; mat < 3; ++mat) {
    const u16* wth = wt + (mat * 2 + 0) * 16384;
    const u16* wtl = wt + (mat * 2 + 1) * 16384;
#pragma unroll
    for (int nf = 0; nf < 2; ++nf) {
      int col = w * 32 + nf * 16 + l16;
      f32x4 acc[2];
      acc[0] = (f32x4){0.f, 0.f, 0.f, 0.f};
      acc[1] = (f32x4){0.f, 0.f, 0.f, 0.f};
#pragma unroll
      for (int kf = 0; kf < 4; ++kf) {
        int d0 = kf * 32 + g * 8;
        bf16x8 bh = *(const bf16x8*)(const void*)(wth + col * 128 + d0);
        bf16x8 bl = *(const bf16x8*)(const void*)(wtl + col * 128 + d0);
#pragma unroll
        for (int mf = 0; mf < 2; ++mf) {
          acc[mf] = __builtin_amdgcn_mfma_f32_16x16x32_bf16(a_h[mf][kf], bh, acc[mf], 0, 0, 0);
          acc[mf] = __builtin_amdgcn_mfma_f32_16x16x32_bf16(a_h[mf][kf], bl, acc[mf], 0, 0, 0);
          acc[mf] = __builtin_amdgcn_mfma_f32_16x16x32_bf16(a_l[mf][kf], bh, acc[mf], 0, 0, 0);
        }
      }
#pragma unroll
      for (int mf = 0; mf < 2; ++mf)
#pragma unroll
        for (int r = 0; r < 4; ++r) {
          int row = tile * 32 + mf * 16 + g * 4 + r;
          float v = acc[mf][r];
          if (mat == 2) {
            VT[((size_t)b * DIM + col) * S_SRC + row] = f2bu(v);
          } else {
            __bf16 h = bf_hi(v);
            __bf16 l = bf_lo(v, h);
            size_t o = ((size_t)b * S_SRC + row) * DIM + col;
            if (mat == 0) { Qh[o] = bfu(h); Ql[o] = bfu(l); }
            else          { Kh[o] = bfu(h); Kl[o] = bfu(l); }
          }
        }
    }
  }
}

// ---------------- kernel 2: flash attention, 8 waves share LDS-staged KV tile ----------------
// Block: 128 q-rows (8 waves x 16), 512 keys (KSPLIT=8). Swapped QK^T (A=K, B=Q).
__global__ __launch_bounds__(512, 4) void k_attn(const u16* __restrict__ Qh, const u16* __restrict__ Ql,
                                                 const u16* __restrict__ Kh, const u16* __restrict__ Kl,
                                                 const u16* __restrict__ VT,
                                                 float* __restrict__ Pm, float* __restrict__ Pl,
                                                 u16* __restrict__ PO) {
  // XCD-aware remap: 512 blocks = 8 XCDs x 64. XCD x gets split x (768KB KV -> its L2).
  const int bid = blockIdx.x;
  const int lid = (bid & 7) * 64 + (bid >> 3);
  const int qb = lid & 63;   // 128-row q-block
  const int sp = lid >> 6;   // kv split 0..7
  const int b = qb >> 5;
  const int tid = threadIdx.x;
  const int w = tid >> 6, lane = tid & 63, g = lane >> 4, l16 = lane & 15;

  __shared__ alignas(16) u16 kbuf[2][8192];   // 16KB each: [hi 32x128 | lo 32x128] swizzled
  __shared__ alignas(16) u16 vbuf[2][4096];   // 8KB each: [128d x 32s] swizzled

  // ---- Q fragments (hi/lo), q-rows qb*128 + w*16 .. +15 ----
  const int gr0 = qb * 128 + w * 16;
  bf16x8 q_h[4], q_l[4];
  {
    const u16* qph = Qh + ((size_t)gr0 + l16) * DIM;
    const u16* qpl = Ql + ((size_t)gr0 + l16) * DIM;
#pragma unroll
    for (int kf = 0; kf < 4; ++kf) {
      int d0 = kf * 32 + g * 8;
      q_h[kf] = *(const bf16x8*)(const void*)(qph + d0);
      q_l[kf] = *(const bf16x8*)(const void*)(qpl + d0);
    }
  }

  f32x4 acc[8];
#pragma unroll
  for (int nf = 0; nf < 8; ++nf) acc[nf] = (f32x4){0.f, 0.f, 0.f, 0.f};
  float m_run = -1e30f, l_run = 0.f;   // stats of q-row l16

  const int key_base = sp * (S_SRC / KSPLIT);
  const u16* KhB = Kh + (size_t)b * S_SRC * DIM;
  const u16* KlB = Kl + (size_t)b * S_SRC * DIM;
  const u16* VTB = VT + (size_t)b * DIM * S_SRC;

  const int kkey = tid >> 4, kcp = tid & 15;                 // K chunk (key, slot)
  const int kcs = (kcp ^ (kkey & 15)) << 3;                  // source d-offset (elems)
  const int vd = tid >> 2, vcp = tid & 3;                    // V chunk (d, slot)
  const int vcs = (vcp ^ ((vd >> 1) & 3)) << 3;              // source s-offset (elems)
  const int wbase = w * 512;                                 // wave-uniform LDS chunk base (u16)

#define STAGE(BUF, KEY0)                                                        \
  {                                                                             \
    const u16* sH = KhB + ((size_t)((KEY0) + kkey)) * DIM + kcs;                \
    const u16* sL = KlB + ((size_t)((KEY0) + kkey)) * DIM + kcs;                \
    const u16* sV = VTB + (size_t)vd * S_SRC + (KEY0) + vcs;                    \
    g2l16(sH, &kbuf[BUF][wbase]);                                               \
    g2l16(sL, &kbuf[BUF][4096 + wbase]);                                        \
    g2l16(sV, &vbuf[BUF][wbase]);                                               \
  }

  STAGE(0, key_base)

  const int mg = ((g & 1) << 1) | (g >> 1);  // V key-chunk permutation {0,2,1,3}
  int cur = 0;
  for (int i = 0; i < S_SRC / KSPLIT / 32; ++i) {
    if (i + 1 < S_SRC / KSPLIT / 32) {
      STAGE(cur ^ 1, key_base + (i + 1) * 32)
      asm volatile("s_waitcnt vmcnt(3)" ::: "memory");
    } else {
      asm volatile("s_waitcnt vmcnt(0)" ::: "memory");
    }
    __builtin_amdgcn_s_barrier();

    // ---- QK^T swapped: rows = keys, cols = q ----
    const u16* kb = kbuf[cur];
    f32x4 s0 = (f32x4){0.f, 0.f, 0.f, 0.f};
    f32x4 s1 = (f32x4){0.f, 0.f, 0.f, 0.f};
    __builtin_amdgcn_s_setprio(1);
#pragma unroll
    for (int kf = 0; kf < 4; ++kf) {
      int cs = ((kf * 4 + g) ^ l16) << 3;
      bf16x8 kh0 = *(const bf16x8*)(const void*)(kb + l16 * 128 + cs);
      bf16x8 kl0 = *(const bf16x8*)(const void*)(kb + 4096 + l16 * 128 + cs);
      bf16x8 kh1 = *(const bf16x8*)(const void*)(kb + (16 + l16) * 128 + cs);
      bf16x8 kl1 = *(const bf16x8*)(const void*)(kb + 4096 + (16 + l16) * 128 + cs);
      s0 = __builtin_amdgcn_mfma_f32_16x16x32_bf16(kh0, q_h[kf], s0, 0, 0, 0);
      s0 = __builtin_amdgcn_mfma_f32_16x16x32_bf16(kh0, q_l[kf], s0, 0, 0, 0);
      s0 = __builtin_amdgcn_mfma_f32_16x16x32_bf16(kl0, q_h[kf], s0, 0, 0, 0);
      s1 = __builtin_amdgcn_mfma_f32_16x16x32_bf16(kh1, q_h[kf], s1, 0, 0, 0);
      s1 = __builtin_amdgcn_mfma_f32_16x16x32_bf16(kh1, q_l[kf], s1, 0, 0, 0);
      s1 = __builtin_amdgcn_mfma_f32_16x16x32_bf16(kl1, q_h[kf], s1, 0, 0, 0);
    }
    __builtin_amdgcn_s_setprio(0);

    // ---- softmax: q-row l16 lane-local over 8 scores + 2 shfl ----
    float mx = fmaxf(fmaxf(fmaxf(s0[0], s0[1]), fmaxf(s0[2], s0[3])),
                     fmaxf(fmaxf(s1[0], s1[1]), fmaxf(s1[2], s1[3])));
    mx = fmaxf(mx, __shfl_xor(mx, 16, 64));
    mx = fmaxf(mx, __shfl_xor(mx, 32, 64));
    // defer-rescale: only rescale when tile max grows past m_run + 8 (exact math either way)
    if (!__all(mx - m_run <= 8.0f)) {
      float mn = fmaxf(m_run, mx);
      float f = __expf(m_run - mn);
      l_run *= f;
      m_run = mn;
      float fr0 = __shfl(f, g * 4 + 0, 64);
      float fr1 = __shfl(f, g * 4 + 1, 64);
      float fr2 = __shfl(f, g * 4 + 2, 64);
      float fr3 = __shfl(f, g * 4 + 3, 64);
#pragma unroll
      for (int nf = 0; nf < 8; ++nf) {
        acc[nf][0] *= fr0; acc[nf][1] *= fr1; acc[nf][2] *= fr2; acc[nf][3] *= fr3;
      }
    }
    float e0 = __expf(s0[0] - m_run), e1 = __expf(s0[1] - m_run);
    float e2 = __expf(s0[2] - m_run), e3 = __expf(s0[3] - m_run);
    float e4 = __expf(s1[0] - m_run), e5 = __expf(s1[1] - m_run);
    float e6 = __expf(s1[2] - m_run), e7 = __expf(s1[3] - m_run);
    float sm = ((e0 + e1) + (e2 + e3)) + ((e4 + e5) + (e6 + e7));
    sm += __shfl_xor(sm, 16, 64);
    sm += __shfl_xor(sm, 32, 64);
    l_run += sm;

    // ---- P -> A-frag: pack pairs, one xor-16 exchange, parity select ----
    u32 w0 = pk2(e0, e1), w1 = pk2(e2, e3), w2 = pk2(e4, e5), w3 = pk2(e6, e7);
    u32 x0 = __shfl_xor(w0, 16, 64), x1 = __shfl_xor(w1, 16, 64);
    u32 x2 = __shfl_xor(w2, 16, 64), x3 = __shfl_xor(w3, 16, 64);
    bool odd = (g & 1);
    u32x4 pw;
    pw.x = odd ? x2 : w0;
    pw.y = odd ? x3 : w1;
    pw.z = odd ? w2 : x0;
    pw.w = odd ? w3 : x1;
    bf16x8 pa = __builtin_bit_cast(bf16x8, pw);

    // ---- PV: O += P * V (V key-slots permuted to match pa) ----
    const u16* vb = vbuf[cur];
    __builtin_amdgcn_s_setprio(1);
#pragma unroll
    for (int nf = 0; nf < 8; ++nf) {
      int d = nf * 16 + l16;
      bf16x8 vf = *(const bf16x8*)(const void*)(vb + d * 32 + ((mg ^ ((d >> 1) & 3)) << 3));
      acc[nf] = __builtin_amdgcn_mfma_f32_16x16x32_bf16(pa, vf, acc[nf], 0, 0, 0);
    }
    __builtin_amdgcn_s_setprio(0);

    __builtin_amdgcn_s_barrier();
    cur ^= 1;
  }

  // ---- write partial (m, l, O) for this (16-row group, split) ----
  const int pidx = sp * NQG + (gr0 >> 4);
  u16* po = PO + (size_t)pidx * 16 * DIM;
#pragma unroll
  for (int nf = 0; nf < 8; ++nf)
#pragma unroll
    for (int r = 0; r < 4; ++r)
      po[(g * 4 + r) * DIM + nf * 16 + l16] = f2bu(acc[nf][r]);
  if (lane < 16) {
    Pm[pidx * 16 + l16] = m_run;
    Pl[pidx * 16 + l16] = l_run;
  }
#undef STAGE
}

// ---------------- kernel 3: combine KV-split partials ----------------
__global__ __launch_bounds__(64) void k_comb(const float* __restrict__ Pm,
                                             const float* __restrict__ Pl,
                                             const u16* __restrict__ PO,
                                             float* __restrict__ out) {
  const int qg = blockIdx.x;
  const int tid = threadIdx.x;

  __shared__ float sc[KSPLIT][16];
  if (tid < 16) {
    float m = -1e30f;
#pragma unroll
    for (int s = 0; s < KSPLIT; ++s) m = fmaxf(m, Pm[(s * NQG + qg) * 16 + tid]);
    float den = 0.f;
    float e[KSPLIT];
#pragma unroll
    for (int s = 0; s < KSPLIT; ++s) {
      e[s] = __expf(Pm[(s * NQG + qg) * 16 + tid] - m);
      den += Pl[(s * NQG + qg) * 16 + tid] * e[s];
    }
    float inv = 1.0f / den;
#pragma unroll
    for (int s = 0; s < KSPLIT; ++s) sc[s][tid] = e[s] * inv;
  }
  __syncthreads();

  float* op = out + (size_t)qg * 16 * DIM;
  for (int i = tid; i < 16 * DIM; i += 64) {
    int row = i >> 7;
    float acc = 0.f;
#pragma unroll
    for (int s = 0; s < KSPLIT; ++s)
      acc += bu2f(PO[(size_t)(s * NQG + qg) * 16 * DIM + i]) * sc[s][row];
    op[i] = acc;
  }
}

extern "C" void kernel_launch(void* const* d_in, const int* in_sizes, int n_in,
                              void* d_out, int out_size, void* d_ws, size_t ws_size,
                              hipStream_t stream) {
  const float* X  = (const float*)d_in[0];
  const float* wq = (const float*)d_in[4];
  const float* wk = (const float*)d_in[5];
  const float* wv = (const float*)d_in[6];
  float* out = (float*)d_out;

  u16* WT = (u16*)d_ws;                       // 3*2*128*128 u16 = 192 KiB
  u16* Qh = WT + 3 * 2 * 128 * 128;
  u16* Ql = Qh + (size_t)BATCH * S_SRC * DIM; // 2 MiB each
  u16* Kh = Ql + (size_t)BATCH * S_SRC * DIM;
  u16* Kl = Kh + (size_t)BATCH * S_SRC * DIM;
  u16* VT = Kl + (size_t)BATCH * S_SRC * DIM; // [B][D][S]
  float* Pm = (float*)(VT + (size_t)BATCH * S_SRC * DIM);  // [KSPLIT*NQG*16] f32
  float* Pl = Pm + (size_t)KSPLIT * NQG * 16;
  u16* PO = (u16*)(Pl + (size_t)KSPLIT * NQG * 16);        // [KSPLIT*NQG*16*128] bf16 = 16 MiB

  hipLaunchKernelGGL(k_wsplit, dim3(192), dim3(256), 0, stream, wq, wk, wv, WT);
  hipLaunchKernelGGL(k_proj, dim3(BATCH * S_SRC / 32), dim3(256), 0, stream,
                     X, WT, Qh, Ql, Kh, Kl, VT);
  hipLaunchKernelGGL(k_attn, dim3(64 * KSPLIT), dim3(512), 0, stream,
                     Qh, Ql, Kh, Kl, VT, Pm, Pl, PO);
  hipLaunchKernelGGL(k_comb, dim3(NQG), dim3(64), 0, stream, Pm, Pl, PO, out);
}